// Round 11
// baseline (658.536 us; speedup 1.0000x reference)
//
#include <hip/hip_runtime.h>
#include <hip/hip_bf16.h>

// B=8, T=2048, D=2048.
//   avg = cumsum(x, axis=T) / (t+1)
//   gates = concat(x, avg) @ W^T + b    (W: [4096][4096])
//   out0 = sig(gates[:, :2048]) * x + sig(gates[:, 2048:]) * avg
// outputs: [out0 fp32] ++ [avg fp32]

#define Bb 8
#define Tt 2048
#define Dd 2048
#define Mm (Bb * Tt)       // 16384
#define Kk 4096
#define NC 32
#define CT 64

typedef __bf16 bf16x8 __attribute__((ext_vector_type(8)));
typedef float f32x4 __attribute__((ext_vector_type(4)));

__device__ __forceinline__ void gload16(const void* g, void* l) {
    __builtin_amdgcn_global_load_lds(
        (const __attribute__((address_space(1))) unsigned int*)g,
        (__attribute__((address_space(3))) unsigned int*)l, 16, 0, 0);
}

// ---------------- K1: W fp32 -> bf16 ----------------
__global__ void wconv_kernel(const float* __restrict__ W,
                             unsigned short* __restrict__ Wb, long n) {
    long i = ((long)blockIdx.x * blockDim.x + threadIdx.x) * 4;
    long stride = (long)gridDim.x * blockDim.x * 4;
    for (; i < n; i += stride) {
        float4 v = *(const float4*)(W + i);
        __hip_bfloat16 a = __float2bfloat16(v.x);
        __hip_bfloat16 b = __float2bfloat16(v.y);
        __hip_bfloat16 c = __float2bfloat16(v.z);
        __hip_bfloat16 d = __float2bfloat16(v.w);
        ushort4 u;
        u.x = *(unsigned short*)&a; u.y = *(unsigned short*)&b;
        u.z = *(unsigned short*)&c; u.w = *(unsigned short*)&d;
        *(ushort4*)(Wb + i) = u;
    }
}

// ---------------- K2: per-chunk sums ----------------
__global__ void ksum_kernel(const float* __restrict__ X, float* __restrict__ S) {
    int d = blockIdx.y * 256 + threadIdx.x;
    int bc = blockIdx.x;
    int b = bc >> 5, c = bc & 31;
    const float* p = X + ((long)(b * Tt + c * CT)) * Dd + d;
    float s = 0.f;
#pragma unroll 8
    for (int t = 0; t < CT; ++t) s += p[(long)t * Dd];
    S[(long)bc * Dd + d] = s;
}

// ---------------- K3: scan + emit avg fp32 + gating_in bf16 ----------------
__global__ void kscan_kernel(const float* __restrict__ X, const float* __restrict__ S,
                             float* __restrict__ AVG, unsigned short* __restrict__ Gin) {
    int d = blockIdx.y * 256 + threadIdx.x;
    int bc = blockIdx.x;
    int b = bc >> 5, c = bc & 31;
    const float* Sp = S + (long)(b * NC) * Dd + d;
    float run = 0.f;
    for (int cc = 0; cc < c; ++cc) run += Sp[(long)cc * Dd];
    const float* p = X + ((long)(b * Tt + c * CT)) * Dd + d;
    long row = (long)b * Tt + c * CT;
    for (int tt = 0; tt < CT; ++tt) {
        float x = p[(long)tt * Dd];
        run += x;
        float av = run / (float)(c * CT + tt + 1);
        long r = row + tt;
        AVG[r * Dd + d] = av;
        __hip_bfloat16 xb = __float2bfloat16(x);
        __hip_bfloat16 ab = __float2bfloat16(av);
        Gin[r * 4096 + d] = *(unsigned short*)&xb;
        Gin[r * 4096 + 2048 + d] = *(unsigned short*)&ab;
    }
}

// ---------------- K4: 8-wave 256x(128d x 2 gates), BK=64, counted-lgkm ------
// vs R8/R10: lgkmcnt(0) -> COUNTED lgkmcnt(N). Per-wave lgkm FIFO is in-order,
// so waiting lgkmcnt(N) completes exactly the oldest batch while the next 1-2
// batches stay in flight under the MFMA clusters (lgkm analog of T4).
// Read batches/tile: RX=aL+bb(8) RY=aH(4) RZ=cL+bd(8) RW=cH(4); prefetch
// RX',RY' for t+1 issued after the boundary barrier (under M3).
// Waits: M0 lgkm(4) | M1 lgkm(8) | M2 lgkm(4) | M3 lgkm(12). vm: mid vmcnt(2),
// boundary vmcnt(4) — never 0 in main loop. 2 barriers/tile. Race audit:
// >=2 barriers separate any buffer-region read from its next staging write.
#define MFMA(va, vb, c_) c_ = __builtin_amdgcn_mfma_f32_16x16x32_bf16(va, vb, c_, 0, 0, 0)
#define RD(p_, i_) (*(const bf16x8*)((p_) + (i_) * 1024))
#define SBAR __builtin_amdgcn_s_barrier()
#define SCHB __builtin_amdgcn_sched_barrier(0)
#define LGKMC(N_) do { asm volatile("s_waitcnt lgkmcnt(" #N_ ")" ::: "memory"); SCHB; } while (0)

#define CLUSTER_LO(A0_,A1_,A2_,A3_,B0_,B1_,B2_,B3_)                             \
    __builtin_amdgcn_s_setprio(1);                                              \
    MFMA(A0_,B0_,acc[0][0]); MFMA(A0_,B1_,acc[0][1]); MFMA(A0_,B2_,acc[0][2]); MFMA(A0_,B3_,acc[0][3]); \
    MFMA(A1_,B0_,acc[1][0]); MFMA(A1_,B1_,acc[1][1]); MFMA(A1_,B2_,acc[1][2]); MFMA(A1_,B3_,acc[1][3]); \
    MFMA(A2_,B0_,acc[2][0]); MFMA(A2_,B1_,acc[2][1]); MFMA(A2_,B2_,acc[2][2]); MFMA(A2_,B3_,acc[2][3]); \
    MFMA(A3_,B0_,acc[3][0]); MFMA(A3_,B1_,acc[3][1]); MFMA(A3_,B2_,acc[3][2]); MFMA(A3_,B3_,acc[3][3]); \
    __builtin_amdgcn_s_setprio(0);
#define CLUSTER_HI(A0_,A1_,A2_,A3_,B0_,B1_,B2_,B3_)                             \
    __builtin_amdgcn_s_setprio(1);                                              \
    MFMA(A0_,B0_,acc[4][0]); MFMA(A0_,B1_,acc[4][1]); MFMA(A0_,B2_,acc[4][2]); MFMA(A0_,B3_,acc[4][3]); \
    MFMA(A1_,B0_,acc[5][0]); MFMA(A1_,B1_,acc[5][1]); MFMA(A1_,B2_,acc[5][2]); MFMA(A1_,B3_,acc[5][3]); \
    MFMA(A2_,B0_,acc[6][0]); MFMA(A2_,B1_,acc[6][1]); MFMA(A2_,B2_,acc[6][2]); MFMA(A2_,B3_,acc[6][3]); \
    MFMA(A3_,B0_,acc[7][0]); MFMA(A3_,B1_,acc[7][1]); MFMA(A3_,B2_,acc[7][2]); MFMA(A3_,B3_,acc[7][3]); \
    __builtin_amdgcn_s_setprio(0);

#define TILE64(t_, bb_, STG_, RDX_, VMs_, VBs_, WM3_)                           \
  {                                                                             \
    const char* pa_ = rA0 + (bb_);                                              \
    const char* pb_ = rB0 + (bb_);                                              \
    const char* qa_ = rA0 + ((bb_) ^ 65536);                                    \
    const char* qb_ = rB0 + ((bb_) ^ 65536);                                    \
    char* nb_ = ldsb + ((bb_) ^ 65536) + woff;                                  \
    const long ko_ = ((long)(t_) + 1) * 128;                                    \
    /* entry: RX(t)+RY(t) outstanding (12) */                                   \
    LGKMC(4);                               /* RX ready; RY in flight */        \
    if (STG_) { gload16(gA0 + ko_, nb_); gload16(gA1 + ko_, nb_ + 8192); }      \
    SCHB;                                                                       \
    CLUSTER_LO(aL0,aL1,aL2,aL3,bb0,bb1,bb2,bb3)        /* M0: kk0 lo */         \
    SCHB;                                                                       \
    asm volatile("s_waitcnt vmcnt(" #VMs_ ")" ::: "memory");                    \
    SBAR; SCHB;                             /* kk1(t) visible */                \
    cL0 = RD(pa_+32768,0); cL1 = RD(pa_+32768,1); cL2 = RD(pa_+32768,2); cL3 = RD(pa_+32768,3); \
    bd0 = RD(pb_+32768,0); bd1 = RD(pb_+32768,1); bd2 = RD(pb_+32768,2); bd3 = RD(pb_+32768,3); \
    SCHB;                                                                       \
    LGKMC(8);                               /* RY ready; RZ in flight */        \
    if (STG_) { gload16(gB0 + ko_, nb_ + 16384); gload16(gB1 + ko_, nb_ + 24576); } \
    SCHB;                                                                       \
    CLUSTER_HI(aH0,aH1,aH2,aH3,bb0,bb1,bb2,bb3)        /* M1: kk0 hi */         \
    SCHB;                                                                       \
    cH0 = RD(pa_+32768,4); cH1 = RD(pa_+32768,5); cH2 = RD(pa_+32768,6); cH3 = RD(pa_+32768,7); \
    SCHB;                                                                       \
    LGKMC(4);                               /* RZ ready; RW in flight */        \
    if (STG_) { gload16(gA0 + ko_ + 64, nb_ + 32768); gload16(gA1 + ko_ + 64, nb_ + 40960); \
                gload16(gB0 + ko_ + 64, nb_ + 49152); gload16(gB1 + ko_ + 64, nb_ + 57344); } \
    SCHB;                                                                       \
    CLUSTER_LO(cL0,cL1,cL2,cL3,bd0,bd1,bd2,bd3)        /* M2: kk1 lo */         \
    SCHB;                                                                       \
    asm volatile("s_waitcnt vmcnt(" #VBs_ ")" ::: "memory");                    \
    SBAR; SCHB;                             /* kk0(t+1) visible */              \
    if (RDX_) {                                                                 \
      aL0 = RD(qa_,0); aL1 = RD(qa_,1); aL2 = RD(qa_,2); aL3 = RD(qa_,3);       \
      bb0 = RD(qb_,0); bb1 = RD(qb_,1); bb2 = RD(qb_,2); bb3 = RD(qb_,3);       \
      aH0 = RD(qa_,4); aH1 = RD(qa_,5); aH2 = RD(qa_,6); aH3 = RD(qa_,7);       \
    }                                                                           \
    SCHB;                                                                       \
    LGKMC(WM3_);                            /* RW ready; RX'+RY' in flight */   \
    CLUSTER_HI(cH0,cH1,cH2,cH3,bd0,bd1,bd2,bd3)        /* M3: kk1 hi */         \
    SCHB;                                                                       \
  }

__global__ __launch_bounds__(512) void gemmcl_kernel(
    const unsigned short* __restrict__ Gin,  // [16384][4096] bf16
    const unsigned short* __restrict__ Wb,   // [4096][4096] bf16
    const float* __restrict__ bias,          // [4096]
    float* __restrict__ OUT)                 // [16384][2048]
{
    __shared__ __attribute__((aligned(128))) char lds[131072]; // 2 x 64KB
    char* ldsb = (char*)lds;

    const int tid = threadIdx.x;
    const int w = tid >> 6, l = tid & 63;
    const int wm = w >> 2, wn = w & 3;       // 2(M) x 4(N) waves
    const int lm = l & 15;
    const int woff = w * 1024;

    // Batch-aware mapping (FETCH-proven): 256-block rounds = 16 m-tiles x
    // 16 n-tiles (A 32MB + W 32MB < L3); per XCD 2 n-tiles (B panel -> L2).
    const int bid = blockIdx.x;
    const int batch = bid >> 8;
    const int rr = bid & 255;
    const int xcd = rr & 7;
    const int j = rr >> 3;
    const int nt = xcd * 2 + (j >> 4);
    const int mt = batch * 16 + (j & 15);
    const long m0 = (long)mt * 256;
    const int n0 = nt * 128;

    // ---- staging addresses (pre-swizzled global chunk; LDS dest linear) ----
    const int srow = tid >> 2;
    const int schunk = (tid & 3) ^ ((tid >> 3) & 3);
    const char* gA0 = (const char*)Gin + (m0 + srow) * 8192 + schunk * 16;
    const char* gA1 = gA0 + 128 * 8192;
    // B tile row j (0..255) -> W row: d-block (j>>6)*32 + (j&31), gate (j>>5)&1
    const long jr0 = n0 + ((srow >> 6) << 5) + (srow & 31) + (((srow >> 5) & 1) << 11);
    const int j1 = 128 + srow;
    const long jr1 = n0 + ((j1 >> 6) << 5) + (j1 & 31) + (((j1 >> 5) & 1) << 11);
    const char* gB0 = (const char*)Wb + jr0 * 8192 + schunk * 16;
    const char* gB1 = (const char*)Wb + jr1 * 8192 + schunk * 16;

    // ---- read addresses (proven 0-conflict swizzle) ----
    const int cbyte = (((l >> 4) ^ ((lm >> 1) & 3))) * 16;
    const char* rA0 = ldsb + (wm * 128 + lm) * 64 + cbyte;          // +bb +kk*32768 +mi*1024
    const char* rB0 = ldsb + 16384 + (wn * 64 + lm) * 64 + cbyte;   // +bb +kk*32768 +nj*1024

    f32x4 acc[8][4] = {};   // [mi][nj]: nj 0-1 gate-i, 2-3 gate-f

    // operand register sets: aL/aH/bb = kk0 (RX,RY); cL/cH/bd = kk1 (RZ,RW)
    bf16x8 aL0, aL1, aL2, aL3, aH0, aH1, aH2, aH3;
    bf16x8 bb0, bb1, bb2, bb3;
    bf16x8 cL0, cL1, cL2, cL3, cH0, cH1, cH2, cH3;
    bf16x8 bd0, bd1, bd2, bd3;

    // prologue: stage tile 0 (Akk0, Bkk0, Akk1, Bkk1) into buf0
    gload16(gA0,      ldsb + woff);
    gload16(gA1,      ldsb + 8192 + woff);
    gload16(gB0,      ldsb + 16384 + woff);
    gload16(gB1,      ldsb + 24576 + woff);
    gload16(gA0 + 64, ldsb + 32768 + woff);
    gload16(gA1 + 64, ldsb + 40960 + woff);
    gload16(gB0 + 64, ldsb + 49152 + woff);
    gload16(gB1 + 64, ldsb + 57344 + woff);
    asm volatile("s_waitcnt vmcnt(4)" ::: "memory");   // kk0(0) landed; kk1 in flight
    SBAR; SCHB;
    // region A for tile 0: issue RX(0)+RY(0)
    aL0 = RD(rA0,0); aL1 = RD(rA0,1); aL2 = RD(rA0,2); aL3 = RD(rA0,3);
    bb0 = RD(rB0,0); bb1 = RD(rB0,1); bb2 = RD(rB0,2); bb3 = RD(rB0,3);
    aH0 = RD(rA0,4); aH1 = RD(rA0,5); aH2 = RD(rA0,6); aH3 = RD(rA0,7);
    SCHB;

#pragma unroll 1
    for (int t = 0; t < 62; t += 2) {     // stages tiles 1..62
        TILE64(t,     0,     1, 1, 2, 4, 12)
        TILE64(t + 1, 65536, 1, 1, 2, 4, 12)
    }
    TILE64(62, 0,     1, 1, 2, 4, 12)     // stages tile 63, prefetch RX(63)
    TILE64(63, 65536, 0, 0, 0, 0, 0)      // tail: full drains

    // ---- fused epilogue (bf16 x/avg from Gin; C/D: col=l&15, row=(l>>4)*4+r)
#pragma unroll
    for (int mi = 0; mi < 8; ++mi) {
        long rbase = m0 + wm * 128 + mi * 16 + (l >> 4) * 4;
#pragma unroll
        for (int nj = 0; nj < 2; ++nj) {
            int d = n0 + wn * 32 + nj * 16 + lm;
            float bi_ = bias[d];
            float bf_ = bias[d + 2048];
#pragma unroll
            for (int r = 0; r < 4; ++r) {
                long row = rbase + r;
                unsigned int ux = Gin[row * 4096 + d];
                unsigned int ua = Gin[row * 4096 + 2048 + d];
                union { unsigned int u; float f; } cx, ca;
                cx.u = ux << 16; ca.u = ua << 16;
                float gi = acc[mi][nj][r] + bi_;
                float gf = acc[mi][nj + 2][r] + bf_;
                float si = 1.f / (1.f + __expf(-gi));
                float sf = 1.f / (1.f + __expf(-gf));
                OUT[row * 2048 + d] = si * cx.f + sf * ca.f;
            }
        }
    }
}

extern "C" void kernel_launch(void* const* d_in, const int* in_sizes, int n_in,
                              void* d_out, int out_size, void* d_ws, size_t ws_size,
                              hipStream_t stream) {
    const float* X = (const float*)d_in[0];     // layer_in [8][2048][2048]
    const float* W = (const float*)d_in[1];     // W_gate [4096][4096]
    const float* bias = (const float*)d_in[2];  // b_gate [4096]

    float* OUT = (float*)d_out;                 // gating_out
    float* AVG = OUT + (long)Mm * Dd;           // average_out

    char* ws = (char*)d_ws;
    unsigned short* Wb  = (unsigned short*)ws;                    // 33,554,432 B
    unsigned short* Gin = (unsigned short*)(ws + 33554432);       // 134,217,728 B
    float* S = (float*)(ws + 33554432 + 134217728);               // 2,097,152 B

    wconv_kernel<<<2048, 256, 0, stream>>>(W, Wb, (long)Kk * Kk);
    ksum_kernel<<<dim3(Bb * NC, Dd / 256), 256, 0, stream>>>(X, S);
    kscan_kernel<<<dim3(Bb * NC, Dd / 256), 256, 0, stream>>>(X, S, AVG, Gin);
    gemmcl_kernel<<<1024, 512, 0, stream>>>(Gin, Wb, bias, OUT);
}

// Round 12
// 641.555 us; speedup vs baseline: 1.0265x; 1.0265x over previous
//
#include <hip/hip_runtime.h>
#include <hip/hip_bf16.h>

// B=8, T=2048, D=2048.
//   avg = cumsum(x, axis=T) / (t+1)
//   gates = concat(x, avg) @ W^T + b    (W: [4096][4096])
//   out0 = sig(gates[:, :2048]) * x + sig(gates[:, 2048:]) * avg
// outputs: [out0 fp32] ++ [avg fp32]

#define Bb 8
#define Tt 2048
#define Dd 2048
#define Mm (Bb * Tt)       // 16384
#define Kk 4096
#define NC 32
#define CT 64

typedef __bf16 bf16x8 __attribute__((ext_vector_type(8)));
typedef float f32x16 __attribute__((ext_vector_type(16)));

__device__ __forceinline__ void gload16(const void* g, void* l) {
    __builtin_amdgcn_global_load_lds(
        (const __attribute__((address_space(1))) unsigned int*)g,
        (__attribute__((address_space(3))) unsigned int*)l, 16, 0, 0);
}

// ---------------- K1: W fp32 -> bf16 ----------------
__global__ void wconv_kernel(const float* __restrict__ W,
                             unsigned short* __restrict__ Wb, long n) {
    long i = ((long)blockIdx.x * blockDim.x + threadIdx.x) * 4;
    long stride = (long)gridDim.x * blockDim.x * 4;
    for (; i < n; i += stride) {
        float4 v = *(const float4*)(W + i);
        __hip_bfloat16 a = __float2bfloat16(v.x);
        __hip_bfloat16 b = __float2bfloat16(v.y);
        __hip_bfloat16 c = __float2bfloat16(v.z);
        __hip_bfloat16 d = __float2bfloat16(v.w);
        ushort4 u;
        u.x = *(unsigned short*)&a; u.y = *(unsigned short*)&b;
        u.z = *(unsigned short*)&c; u.w = *(unsigned short*)&d;
        *(ushort4*)(Wb + i) = u;
    }
}

// ---------------- K2: per-chunk sums ----------------
__global__ void ksum_kernel(const float* __restrict__ X, float* __restrict__ S) {
    int d = blockIdx.y * 256 + threadIdx.x;
    int bc = blockIdx.x;
    int b = bc >> 5, c = bc & 31;
    const float* p = X + ((long)(b * Tt + c * CT)) * Dd + d;
    float s = 0.f;
#pragma unroll 8
    for (int t = 0; t < CT; ++t) s += p[(long)t * Dd];
    S[(long)bc * Dd + d] = s;
}

// ---------------- K3: scan + emit avg fp32 + gating_in bf16 ----------------
__global__ void kscan_kernel(const float* __restrict__ X, const float* __restrict__ S,
                             float* __restrict__ AVG, unsigned short* __restrict__ Gin) {
    int d = blockIdx.y * 256 + threadIdx.x;
    int bc = blockIdx.x;
    int b = bc >> 5, c = bc & 31;
    const float* Sp = S + (long)(b * NC) * Dd + d;
    float run = 0.f;
    for (int cc = 0; cc < c; ++cc) run += Sp[(long)cc * Dd];
    const float* p = X + ((long)(b * Tt + c * CT)) * Dd + d;
    long row = (long)b * Tt + c * CT;
    for (int tt = 0; tt < CT; ++tt) {
        float x = p[(long)tt * Dd];
        run += x;
        float av = run / (float)(c * CT + tt + 1);
        long r = row + tt;
        AVG[r * Dd + d] = av;
        __hip_bfloat16 xb = __float2bfloat16(x);
        __hip_bfloat16 ab = __float2bfloat16(av);
        Gin[r * 4096 + d] = *(unsigned short*)&xb;
        Gin[r * 4096 + 2048 + d] = *(unsigned short*)&ab;
    }
}

// ---------------- K4: 8-wave 256x(128d x 2 gates), BK=64, 32x32x16 MFMA -----
// vs R8: (1) mfma_f32_32x32x16_bf16 (2495 vs 2075 TF ubench; half the MFMA
// instructions); A/B fragment layouts + dual-gate epilogue verified in R3.
// (2) 8-chunk XOR swizzle on 128B rows: stored chunk p of row r holds global
// chunk q = p ^ (r&7). Frag reads (32 rows, 16B each): 8 groups x 4 lanes ->
// 4 accesses/bank over all 32 banks = minimal. Staging pre-swizzles the
// GLOBAL source; LDS dest stays linear for global_load_lds.
// (3) ONE barrier + ONE vmcnt per tile: stage all 8 lines of t+1 in phase 0
// (that buffer's reads were sealed a barrier ago); boundary vmcnt(0)+lgkm(0)
// after phase 2 — drain cheap (issue distance ~2 phases >> L2 latency);
// phase 3 prefetches t+1 kq0 operands after the barrier.
// Phases: kq=0..3; reads for kq+1 issued before MFMA(kq); P=even kq, Q=odd.
#define MFMA32(va, vb, c_) c_ = __builtin_amdgcn_mfma_f32_32x32x16_bf16(va, vb, c_, 0, 0, 0)
#define SBAR __builtin_amdgcn_s_barrier()
#define SCHB __builtin_amdgcn_sched_barrier(0)
#define LGKM0 do { asm volatile("s_waitcnt lgkmcnt(0)" ::: "memory"); SCHB; } while (0)

#define READ6(S_, pA_, pB_)                                                     \
    S_##a0 = *(const bf16x8*)(pA_);                                             \
    S_##a1 = *(const bf16x8*)((pA_) + 4096);                                    \
    S_##a2 = *(const bf16x8*)((pA_) + 8192);                                    \
    S_##a3 = *(const bf16x8*)((pA_) + 12288);                                   \
    S_##b0 = *(const bf16x8*)(pB_);                                             \
    S_##b1 = *(const bf16x8*)((pB_) + 4096);

#define CLUST(S_)                                                               \
    __builtin_amdgcn_s_setprio(1);                                              \
    MFMA32(S_##a0, S_##b0, acc[0][0]); MFMA32(S_##a0, S_##b1, acc[0][1]);       \
    MFMA32(S_##a1, S_##b0, acc[1][0]); MFMA32(S_##a1, S_##b1, acc[1][1]);       \
    MFMA32(S_##a2, S_##b0, acc[2][0]); MFMA32(S_##a2, S_##b1, acc[2][1]);       \
    MFMA32(S_##a3, S_##b0, acc[3][0]); MFMA32(S_##a3, S_##b1, acc[3][1]);       \
    __builtin_amdgcn_s_setprio(0);

#define STAGE8(nw_, ko_)                                                        \
    gload16(gA0 + (ko_),           (nw_));                                      \
    gload16(gA0 + 524288 + (ko_),  (nw_) + 8192);                               \
    gload16(gA0 + 1048576 + (ko_), (nw_) + 16384);                              \
    gload16(gA0 + 1572864 + (ko_), (nw_) + 24576);                              \
    gload16(gB0 + (ko_),           (nw_) + 32768);                              \
    gload16(gB0 + 262144 + (ko_),  (nw_) + 40960);                              \
    gload16(gB0 + 524288 + (ko_),  (nw_) + 49152);                              \
    gload16(gB0 + 786432 + (ko_),  (nw_) + 57344);

#define TILE32(t_, bb_, STG_, RDX_)                                             \
  {                                                                             \
    const char* b_ = ldsb + (bb_);                                              \
    const char* nb_ = ldsb + ((bb_) ^ 65536);                                   \
    char* nw_ = ldsb + ((bb_) ^ 65536) + woff;                                  \
    const long ko_ = ((long)(t_) + 1) * 128;                                    \
    /* PH0: wait kq0(P); read kq1->Q; stage all 8 lines of t+1; MFMA kq0 */     \
    LGKM0;                                                                      \
    READ6(q, b_ + rAk1, b_ + rBk1)                                              \
    if (STG_) { STAGE8(nw_, ko_) }                                              \
    CLUST(p)                                                                    \
    /* PH1: wait kq1(Q); read kq2->P; MFMA kq1 */                               \
    LGKM0;                                                                      \
    READ6(p, b_ + rAk2, b_ + rBk2)                                              \
    CLUST(q)                                                                    \
    /* PH2: wait kq2(P); read kq3->Q; MFMA kq2 */                               \
    LGKM0;                                                                      \
    READ6(q, b_ + rAk3, b_ + rBk3)                                              \
    CLUST(p)                                                                    \
    /* boundary: staging of t+1 drained; buffer swap visible */                 \
    asm volatile("s_waitcnt vmcnt(0) lgkmcnt(0)" ::: "memory");                 \
    SBAR; SCHB;                                                                 \
    /* PH3: prefetch kq0(t+1)->P from other buf; MFMA kq3 */                    \
    if (RDX_) { READ6(p, nb_ + rAk0, nb_ + rBk0) }                              \
    SCHB;                                                                       \
    CLUST(q)                                                                    \
    SCHB;                                                                       \
  }

__global__ __launch_bounds__(512) void gemm32s_kernel(
    const unsigned short* __restrict__ Gin,  // [16384][4096] bf16
    const unsigned short* __restrict__ Wb,   // [4096][4096] bf16
    const float* __restrict__ bias,          // [4096]
    float* __restrict__ OUT)                 // [16384][2048]
{
    __shared__ __attribute__((aligned(128))) char lds[131072]; // 2 x (A32K+B32K)
    char* ldsb = (char*)lds;

    const int tid = threadIdx.x;
    const int w = tid >> 6, l = tid & 63;
    const int wm = w >> 2, wn = w & 3;       // 2(M) x 4(N) waves
    const int la = l & 31;                   // fragment row/col
    const int lk = l >> 5;                   // k half (k = lk*8 + j)
    const int woff = w * 1024;

    // Batch-aware mapping (FETCH-proven): 256-block rounds = 16 m-tiles x
    // 16 n-tiles (A 32MB + W 32MB < L3); per XCD 2 n-tiles (B panel -> L2).
    const int bid = blockIdx.x;
    const int batch = bid >> 8;
    const int rr = bid & 255;
    const int xcd = rr & 7;
    const int j = rr >> 3;
    const int nt = xcd * 2 + (j >> 4);
    const int mt = batch * 16 + (j & 15);
    const long m0 = (long)mt * 256;
    const int n0 = nt * 128;

    // ---- staging source (pre-swizzled chunk; LDS dest linear) ----
    // line = 64 rows x 128B = 8KB = 512 thr x 16B. row-in-line = tid>>3,
    // position p = tid&7 holds global chunk q = p ^ (row&7).
    const int srow8 = tid >> 3;
    const int sq = (tid & 7) ^ (srow8 & 7);
    const char* gA0 = (const char*)Gin + (m0 + srow8) * 8192 + sq * 16;
    // B logical row j0 = line*64 + srow8 -> W row n0 + line*32 + (srow8&31)
    //   + ((srow8>>5)&1)*2048 ; line stride = 32 W-rows = 262144 B.
    const char* gB0 = (const char*)Wb
        + ((long)(n0 + (srow8 & 31) + ((srow8 >> 5) << 11))) * 8192 + sq * 16;

    // ---- read offsets: frag(mi,kq): row R = wm*128+mi*32+la, chunk q=kq*2+lk
    //      at position q ^ (R&7); R&7 == la&7. addr = R*128 + pos*16.
    //      (base + mi*4096) ^ (kq*32) gives all frags.
    const int c0 = (lk ^ (la & 7)) << 4;
    const int rAbase = (wm * 128 + la) * 128 + c0;
    const int rBbase = 32768 + (wn * 64 + la) * 128 + c0;
    const int rAk0 = rAbase;        const int rBk0 = rBbase;
    const int rAk1 = rAbase ^ 32;   const int rBk1 = rBbase ^ 32;
    const int rAk2 = rAbase ^ 64;   const int rBk2 = rBbase ^ 64;
    const int rAk3 = rAbase ^ 96;   const int rBk3 = rBbase ^ 96;

    f32x16 acc[4][2] = {};   // [mi][gate]: 0=input, 1=forget (same d cols)

    // operand sets: p = even kq, q = odd kq
    bf16x8 pa0, pa1, pa2, pa3, pb0, pb1;
    bf16x8 qa0, qa1, qa2, qa3, qb0, qb1;

    // prologue: stage tile 0 into buf0; then issue kq0 reads
    {
        char* w0 = ldsb + woff;
        STAGE8(w0, 0)
    }
    asm volatile("s_waitcnt vmcnt(0)" ::: "memory");
    SBAR; SCHB;
    READ6(p, ldsb + rAk0, ldsb + rBk0)
    SCHB;

#pragma unroll 1
    for (int t = 0; t < 62; t += 2) {     // stages tiles 1..62
        TILE32(t,     0,     1, 1)
        TILE32(t + 1, 65536, 1, 1)
    }
    TILE32(62, 0,     1, 1)               // stages tile 63
    TILE32(63, 65536, 0, 0)               // tail

    // ---- fused epilogue (R3-verified 32x32 C/D map + bf16 x/avg from Gin)
    // C/D: col = lane&31, row = (q&3) + 8*(q>>2) + 4*(lane>>5)
    const int d = n0 + wn * 32 + la;
    const float bi_ = bias[d];
    const float bf_ = bias[d + 2048];
#pragma unroll
    for (int mi = 0; mi < 4; ++mi) {
        const long rb = m0 + wm * 128 + mi * 32 + lk * 4;
        f32x16 ci = acc[mi][0];
        f32x16 cf = acc[mi][1];
#pragma unroll
        for (int qq = 0; qq < 16; ++qq) {
            long row = rb + (qq & 3) + 8 * (qq >> 2);
            unsigned int ux = Gin[row * 4096 + d];
            unsigned int ua = Gin[row * 4096 + 2048 + d];
            union { unsigned int u; float f; } cx, ca;
            cx.u = ux << 16; ca.u = ua << 16;
            float gi = ci[qq] + bi_;
            float gf = cf[qq] + bf_;
            float si = 1.f / (1.f + __expf(-gi));
            float sf = 1.f / (1.f + __expf(-gf));
            OUT[row * 2048 + d] = si * cx.f + sf * ca.f;
        }
    }
}

extern "C" void kernel_launch(void* const* d_in, const int* in_sizes, int n_in,
                              void* d_out, int out_size, void* d_ws, size_t ws_size,
                              hipStream_t stream) {
    const float* X = (const float*)d_in[0];     // layer_in [8][2048][2048]
    const float* W = (const float*)d_in[1];     // W_gate [4096][4096]
    const float* bias = (const float*)d_in[2];  // b_gate [4096]

    float* OUT = (float*)d_out;                 // gating_out
    float* AVG = OUT + (long)Mm * Dd;           // average_out

    char* ws = (char*)d_ws;
    unsigned short* Wb  = (unsigned short*)ws;                    // 33,554,432 B
    unsigned short* Gin = (unsigned short*)(ws + 33554432);       // 134,217,728 B
    float* S = (float*)(ws + 33554432 + 134217728);               // 2,097,152 B

    wconv_kernel<<<2048, 256, 0, stream>>>(W, Wb, (long)Kk * Kk);
    ksum_kernel<<<dim3(Bb * NC, Dd / 256), 256, 0, stream>>>(X, S);
    kscan_kernel<<<dim3(Bb * NC, Dd / 256), 256, 0, stream>>>(X, S, AVG, Gin);
    gemm32s_kernel<<<1024, 512, 0, stream>>>(Gin, Wb, bias, OUT);
}